// Round 19
// baseline (395.243 us; speedup 1.0000x reference)
//
#include <hip/hip_runtime.h>
#include <math.h>

#define N_NODES 100000
#define N_GRAPHS 512
#define EMB 64
#define NBKT 196         // ceil(100000 / 512) buckets of 512 nodes
#define BSH 9            // bucket shift (512 nodes)
#define CHUNK_E 4096     // edges per k_bscatter block

typedef unsigned int uint;
typedef __fp16 half_t;
typedef half_t h2_t __attribute__((ext_vector_type(2)));

__device__ __forceinline__ h2_t uint_as_h2(uint u) {
    union { uint u; h2_t h; } c; c.u = u; return c.h;
}
__device__ __forceinline__ uint h2_as_uint(h2_t h) {
    union { uint u; h2_t h; } c; c.h = h; return c.u;
}
__device__ __forceinline__ uint packh2(float a, float b) {
    return h2_as_uint(__builtin_amdgcn_cvt_pkrtz(a, b));
}

#if __has_builtin(__builtin_amdgcn_fdot2)
#define FDOT2(a, b, c) __builtin_amdgcn_fdot2((a), (b), (c), false)
#else
__device__ __forceinline__ float FDOT2(h2_t a, h2_t b, float c) {
    return c + (float)a[0] * (float)b[0] + (float)a[1] * (float)b[1];
}
#endif

// ---------------- bf16 pack/unpack ----------------
__device__ __forceinline__ float bflo(uint u) { return __uint_as_float(u << 16); }
__device__ __forceinline__ float bfhi(uint u) { return __uint_as_float(u & 0xffff0000u); }
__device__ __forceinline__ uint rne16(float f) {
    uint u = __float_as_uint(f);
    return (u + 0x7fffu + ((u >> 16) & 1u)) >> 16;
}
__device__ __forceinline__ uint pack2(float a, float b) {
    return rne16(a) | (rne16(b) << 16);
}

// ---------------- utility ----------------
__global__ void k_zero_i(int* __restrict__ p, int n) {
    int i = blockIdx.x * blockDim.x + threadIdx.x;
    int stride = gridDim.x * blockDim.x;
    for (; i < n; i += stride) p[i] = 0;
}

// bucket histogram of dst>>BSH, LDS-staged
__global__ __launch_bounds__(256) void k_bhist(const int* __restrict__ dst, int E,
                                               int* __restrict__ bcnt) {
    __shared__ int w[NBKT];
    for (int i = threadIdx.x; i < NBKT; i += 256) w[i] = 0;
    __syncthreads();
    int i = blockIdx.x * 256 + threadIdx.x;
    int stride = gridDim.x * 256;
    for (; i < E; i += stride) atomicAdd(&w[dst[i] >> BSH], 1);
    __syncthreads();
    for (int t = threadIdx.x; t < NBKT; t += 256)
        if (w[t]) atomicAdd(&bcnt[t], w[t]);
}

__global__ void k_bscan(const int* __restrict__ bcnt, int* __restrict__ bstart,
                        int* __restrict__ bcursor) {
    if (blockIdx.x == 0 && threadIdx.x == 0) {
        int run = 0;
        for (int b = 0; b < NBKT; ++b) { bstart[b] = run; bcursor[b] = run; run += bcnt[b]; }
        bstart[NBKT] = run;
    }
}

// counting-sort pass: partition edges into dst-buckets with LDS staging so
// global writes are coalesced per-bucket runs.
// sp[pos] = (src << 9) | (dst & 511)   (26 bits used)
__global__ __launch_bounds__(256) void k_bscatter(
    const int* __restrict__ src, const int* __restrict__ dst, int E,
    int* __restrict__ bcursor, uint* __restrict__ sp) {
    __shared__ int wcnt[NBKT];
    __shared__ int wbase[NBKT];
    __shared__ int lofs[NBKT];
    __shared__ int lcur[NBKT];
    __shared__ uint stage[CHUNK_E];
    __shared__ short sbkt[CHUNK_E];

    int e0 = blockIdx.x * CHUNK_E;
    int e1 = e0 + CHUNK_E;
    if (e1 > E) e1 = E;
    int t = threadIdx.x;

    for (int i = t; i < NBKT; i += 256) { wcnt[i] = 0; lcur[i] = 0; }
    __syncthreads();
    for (int i = e0 + t; i < e1; i += 256) atomicAdd(&wcnt[dst[i] >> BSH], 1);
    __syncthreads();
    if (t < NBKT) wbase[t] = atomicAdd(&bcursor[t], wcnt[t]);
    if (t == 0) {
        int run = 0;
        for (int b = 0; b < NBKT; ++b) { lofs[b] = run; run += wcnt[b]; }
    }
    __syncthreads();
    for (int i = e0 + t; i < e1; i += 256) {
        int d = dst[i];
        int b = d >> BSH;
        int l = lofs[b] + atomicAdd(&lcur[b], 1);
        stage[l] = ((uint)src[i] << BSH) | (uint)(d & 511);
        sbkt[l] = (short)b;
    }
    __syncthreads();
    int n = e1 - e0;
    for (int k = t; k < n; k += 256) {
        int b = sbkt[k];
        sp[wbase[b] + (k - lofs[b])] = stage[k];
    }
}

// fused CSR finalize, one block per 512-node bucket, 1 thread per node:
// LDS histogram -> shuffle scan (bucket base = bstart[b]) -> rowptr/dsq -> scatter
__global__ __launch_bounds__(512) void k_csr(const uint* __restrict__ sp,
                                             const int* __restrict__ bstart,
                                             int* __restrict__ rowptr,
                                             float* __restrict__ dsq,
                                             int* __restrict__ csr) {
    __shared__ int lcnt[512];
    __shared__ int wsum[8];
    int b = blockIdx.x, base = b << BSH, t = threadIdx.x;
    lcnt[t] = 0;
    __syncthreads();
    int s0 = bstart[b], s1 = bstart[b + 1];
    for (int i = s0 + t; i < s1; i += 512) atomicAdd(&lcnt[sp[i] & 511u], 1);
    __syncthreads();
    int c = lcnt[t];
    int lane = t & 63, wid = t >> 6;
    int inc = c;
    for (int off = 1; off < 64; off <<= 1) {
        int v = __shfl_up(inc, off, 64);
        if (lane >= off) inc += v;
    }
    if (lane == 63) wsum[wid] = inc;
    __syncthreads();
    int wbase = 0;
    for (int w = 0; w < wid; ++w) wbase += wsum[w];
    int p = s0 + wbase + inc - c;
    int n = base + t;
    lcnt[t] = p;    // becomes this node's scatter cursor
    if (n < N_NODES) { rowptr[n] = p; dsq[n] = rsqrtf((float)c + 1.0f); }
    if (b == NBKT - 1 && t == 511) rowptr[N_NODES] = s1;
    __syncthreads();
    for (int i = s0 + t; i < s1; i += 512) {
        uint pr = sp[i];
        int pos = atomicAdd(&lcnt[pr & 511u], 1);
        csr[pos] = (int)(pr >> BSH);
    }
}

// graph boundary detection on sorted batch index -> gstart[0..N_GRAPHS]
__global__ void k_gbound(const int* __restrict__ batch, int* __restrict__ gstart) {
    int i = blockIdx.x * blockDim.x + threadIdx.x;
    if (i >= N_NODES) return;
    int b = batch[i];
    if (i == 0) {
        for (int g = 0; g <= b; ++g) gstart[g] = 0;
    } else {
        int pb = batch[i - 1];
        for (int g = pb + 1; g <= b; ++g) gstart[g] = i;
    }
    if (i == N_NODES - 1) {
        for (int g = b + 1; g <= N_GRAPHS; ++g) gstart[g] = N_NODES;
    }
}

// xp2 = packed bf16 of dsq[n]*x, padded to 16 channels (8 uints / 4 uint2 per node)
__global__ void k_xprep2(const float* __restrict__ x, const float* __restrict__ dsq,
                         uint* __restrict__ xp2) {
    int i = blockIdx.x * blockDim.x + threadIdx.x;
    int stride = gridDim.x * blockDim.x;
    const int total = N_NODES * 8;
    for (; i < total; i += stride) {
        int n = i >> 3, u = i & 7;
        int c0 = 2 * u, c1 = c0 + 1;
        float d = dsq[n];
        float v0 = (c0 < 12) ? x[n * 12 + c0] * d : 0.0f;
        float v1 = (c1 < 12) ? x[n * 12 + c1] * d : 0.0f;
        xp2[i] = pack2(v0, v1);
    }
}

// fp8 epilogue pack: lane holds channel `lane` value sv (already x16 scaled);
// produces one uint per 4 lanes.
__device__ __forceinline__ void store_fp8_row(uint* __restrict__ hout, int node,
                                              int lane, float sv) {
    float pv = __shfl_xor(sv, 1, 64);
    uint w = (uint)__builtin_amdgcn_cvt_pk_fp8_f32(sv, pv, 0, false);
    uint w2 = __shfl_xor(w, 2, 64);
    if ((lane & 3) == 0) hout[node * 16 + (lane >> 2)] = (w & 0xffffu) | (w2 << 16);
}

// pure gather+reduce: fp8 rows in, f16 aggregated row out (128B coalesced).
// 8 independent loads in flight per lane (full 64-edge body, straight-line);
// no LDS matmul pressure -> VGPR stays under the 64-reg wave boundary.
__global__ __launch_bounds__(256) void k_agg(
    const int* __restrict__ rowptr, const int* __restrict__ csr,
    const float* __restrict__ dsq, const uint2* __restrict__ hin,
    uint* __restrict__ aggout) {
    int wid = threadIdx.x >> 6;
    int lane = threadIdx.x & 63;
    int q = lane >> 3;       // edge slot 0..7
    int cc = lane & 7;       // uint2 index in row -> channels 8cc..8cc+7

    int node = blockIdx.x * 4 + wid;
    int start = rowptr[node], end = rowptr[node + 1];
    float dn = dsq[node];

    float a0 = 0.0f, a1 = 0.0f, a2 = 0.0f, a3 = 0.0f;
    float a4 = 0.0f, a5 = 0.0f, a6 = 0.0f, a7 = 0.0f;
#define ACCU(u) do { \
        auto f0 = __builtin_amdgcn_cvt_pk_f32_fp8(u.x, false); \
        auto f1 = __builtin_amdgcn_cvt_pk_f32_fp8(u.x, true);  \
        auto f2 = __builtin_amdgcn_cvt_pk_f32_fp8(u.y, false); \
        auto f3 = __builtin_amdgcn_cvt_pk_f32_fp8(u.y, true);  \
        a0 += f0[0]; a1 += f0[1]; a2 += f1[0]; a3 += f1[1]; \
        a4 += f2[0]; a5 += f2[1]; a6 += f3[0]; a7 += f3[1]; } while (0)

    if (q == 0) {
        uint2 u = hin[node * 8 + cc];       // self-loop
        ACCU(u);
    }

    for (int k0 = start; k0 < end; k0 += 64) {
        int idx = k0 + lane;
        int s = (idx < end) ? csr[idx] : 0;
        int nk = end - k0; if (nk > 64) nk = 64;
        int s0 = __shfl(s, q, 64);
        int s1 = __shfl(s, 8 + q, 64);
        int s2 = __shfl(s, 16 + q, 64);
        int s3 = __shfl(s, 24 + q, 64);
        int s4 = __shfl(s, 32 + q, 64);
        int s5 = __shfl(s, 40 + q, 64);
        int s6 = __shfl(s, 48 + q, 64);
        int s7 = __shfl(s, 56 + q, 64);
        uint2 u0 = make_uint2(0u, 0u), u1 = make_uint2(0u, 0u);
        uint2 u2 = make_uint2(0u, 0u), u3 = make_uint2(0u, 0u);
        uint2 u4 = make_uint2(0u, 0u), u5 = make_uint2(0u, 0u);
        uint2 u6 = make_uint2(0u, 0u), u7 = make_uint2(0u, 0u);
        if (q < nk)      u0 = hin[s0 * 8 + cc];
        if (8 + q < nk)  u1 = hin[s1 * 8 + cc];
        if (16 + q < nk) u2 = hin[s2 * 8 + cc];
        if (24 + q < nk) u3 = hin[s3 * 8 + cc];
        if (32 + q < nk) u4 = hin[s4 * 8 + cc];
        if (40 + q < nk) u5 = hin[s5 * 8 + cc];
        if (48 + q < nk) u6 = hin[s6 * 8 + cc];
        if (56 + q < nk) u7 = hin[s7 * 8 + cc];
        ACCU(u0); ACCU(u1); ACCU(u2); ACCU(u3);
        ACCU(u4); ACCU(u5); ACCU(u6); ACCU(u7);
    }
#undef ACCU
#define RED(a) a += __shfl_xor(a, 8, 64); a += __shfl_xor(a, 16, 64); a += __shfl_xor(a, 32, 64)
    RED(a0); RED(a1); RED(a2); RED(a3); RED(a4); RED(a5); RED(a6); RED(a7);
#undef RED
    if (q == 0) {
        float g = dn * (1.0f / 16.0f);
        uint4 pk;
        pk.x = packh2(g * a0, g * a1);
        pk.y = packh2(g * a2, g * a3);
        pk.z = packh2(g * a4, g * a5);
        pk.w = packh2(g * a6, g * a7);
        *(uint4*)&aggout[node * 32 + cc * 4] = pk;
    }
}

// streaming matmul + activation + fp8 pack: reads f16 agg rows, W in VGPRs.
// Grid-strided; occupancy-insensitive (stream-bound).
template <int ACT, int LAST>
__global__ __launch_bounds__(256) void k_mmact(
    const float* __restrict__ dsq, const uint* __restrict__ agg,
    const float* __restrict__ W, const float* __restrict__ b,
    uint* __restrict__ hout, float* __restrict__ houtf) {
    __shared__ uint rowsh[4][32];

    int wid = threadIdx.x >> 6;
    int lane = threadIdx.x & 63;

    uint wreg[32];
#pragma unroll
    for (int m = 0; m < 32; ++m)
        wreg[m] = packh2(W[(2 * m) * 64 + lane], W[(2 * m + 1) * 64 + lane]);
    float bias = b[lane];

    for (int grp = blockIdx.x; grp < N_NODES / 4; grp += gridDim.x) {
        int node = grp * 4 + wid;
        // coalesced 128B row load: lanes 0..31 load one uint each
        if (lane < 32) rowsh[wid][lane] = agg[node * 32 + lane];
        // same-wave producer/consumer: LDS ops in-order, no barrier needed

        float sacc = bias;
#pragma unroll
        for (int j = 0; j < 8; ++j) {
            uint4 r = *(const uint4*)&rowsh[wid][4 * j];
            sacc = FDOT2(uint_as_h2(r.x), uint_as_h2(wreg[4 * j + 0]), sacc);
            sacc = FDOT2(uint_as_h2(r.y), uint_as_h2(wreg[4 * j + 1]), sacc);
            sacc = FDOT2(uint_as_h2(r.z), uint_as_h2(wreg[4 * j + 2]), sacc);
            sacc = FDOT2(uint_as_h2(r.w), uint_as_h2(wreg[4 * j + 3]), sacc);
        }
        float val = ACT ? fmaxf(sacc, 0.0f) : (sacc > 0.0f ? sacc : 0.01f * sacc);

        if (LAST) {
            houtf[node * 64 + lane] = val;
        } else {
            store_fp8_row(hout, node, lane, 16.0f * dsq[node] * val);
        }
    }
}

// layer 0: pull-aggregate bf16 xp2 (16-ch padded, uint2, 16 edge-slots,
// 4 loads in flight = 64 edges/iter) + 12x64 matmul + leaky, fp8 packed out
__global__ __launch_bounds__(256) void k_layer12(
    const int* __restrict__ rowptr, const int* __restrict__ csr,
    const float* __restrict__ dsq, const uint2* __restrict__ xp2,
    const float* __restrict__ W, const float* __restrict__ b,
    uint* __restrict__ hout) {
    __shared__ float Wl[12 * 64];
    __shared__ float rows[4][16];
    for (int i = threadIdx.x; i < 12 * 64; i += 256) Wl[i] = W[i];

    int wid = threadIdx.x >> 6;
    int lane = threadIdx.x & 63;
    int node = blockIdx.x * 4 + wid;
    int q = lane >> 2;       // edge slot 0..15
    int cc = lane & 3;       // uint2 index -> channels 4cc..4cc+3 (of 16)

    int start = rowptr[node], end = rowptr[node + 1];
    float dn = dsq[node];

    float a0 = 0.0f, a1 = 0.0f, a2 = 0.0f, a3 = 0.0f;
    if (q == 0) {
        uint2 u = xp2[node * 4 + cc];
        a0 = bflo(u.x); a1 = bfhi(u.x); a2 = bflo(u.y); a3 = bfhi(u.y);
    }

    for (int k0 = start; k0 < end; k0 += 64) {
        int idx = k0 + lane;
        int s = (idx < end) ? csr[idx] : 0;
        int nk = end - k0; if (nk > 64) nk = 64;
        int s0 = __shfl(s, q, 64);
        int s1 = __shfl(s, 16 + q, 64);
        int s2 = __shfl(s, 32 + q, 64);
        int s3 = __shfl(s, 48 + q, 64);
        uint2 u0 = make_uint2(0u, 0u), u1 = make_uint2(0u, 0u);
        uint2 u2 = make_uint2(0u, 0u), u3 = make_uint2(0u, 0u);
        if (q < nk)      u0 = xp2[s0 * 4 + cc];
        if (16 + q < nk) u1 = xp2[s1 * 4 + cc];
        if (32 + q < nk) u2 = xp2[s2 * 4 + cc];
        if (48 + q < nk) u3 = xp2[s3 * 4 + cc];
        a0 += bflo(u0.x); a1 += bfhi(u0.x); a2 += bflo(u0.y); a3 += bfhi(u0.y);
        a0 += bflo(u1.x); a1 += bfhi(u1.x); a2 += bflo(u1.y); a3 += bfhi(u1.y);
        a0 += bflo(u2.x); a1 += bfhi(u2.x); a2 += bflo(u2.y); a3 += bfhi(u2.y);
        a0 += bflo(u3.x); a1 += bfhi(u3.x); a2 += bflo(u3.y); a3 += bfhi(u3.y);
    }
    a0 += __shfl_xor(a0, 4, 64); a0 += __shfl_xor(a0, 8, 64);
    a0 += __shfl_xor(a0, 16, 64); a0 += __shfl_xor(a0, 32, 64);
    a1 += __shfl_xor(a1, 4, 64); a1 += __shfl_xor(a1, 8, 64);
    a1 += __shfl_xor(a1, 16, 64); a1 += __shfl_xor(a1, 32, 64);
    a2 += __shfl_xor(a2, 4, 64); a2 += __shfl_xor(a2, 8, 64);
    a2 += __shfl_xor(a2, 16, 64); a2 += __shfl_xor(a2, 32, 64);
    a3 += __shfl_xor(a3, 4, 64); a3 += __shfl_xor(a3, 8, 64);
    a3 += __shfl_xor(a3, 16, 64); a3 += __shfl_xor(a3, 32, 64);
    if (q == 0) {
        rows[wid][4 * cc + 0] = dn * a0;
        rows[wid][4 * cc + 1] = dn * a1;
        rows[wid][4 * cc + 2] = dn * a2;
        rows[wid][4 * cc + 3] = dn * a3;
    }
    __syncthreads();

    float sacc = b[lane];
#pragma unroll
    for (int k = 0; k < 12; ++k) sacc += rows[wid][k] * Wl[k * 64 + lane];
    float val = (sacc > 0.0f) ? sacc : 0.01f * sacc;
    store_fp8_row(hout, node, lane, 16.0f * dn * val);
}

// fused mean-pool + FC + sigmoid: one block per graph, float4 loads,
// no atomics (range from gstart)
__global__ __launch_bounds__(256) void k_poolfc(
    const float* __restrict__ h, const int* __restrict__ gstart,
    const float* __restrict__ Wfc, const float* __restrict__ bfc,
    float* __restrict__ out) {
    __shared__ float sums[4][64];
    int g = blockIdx.x;
    int t = threadIdx.x;
    int w = t >> 6, lane = t & 63;
    int q = lane & 15, sub = lane >> 4;
    int s0 = gstart[g], s1 = gstart[g + 1];

    float a0 = 0.0f, a1 = 0.0f, a2 = 0.0f, a3 = 0.0f;
    for (int n = s0 + w * 4 + sub; n < s1; n += 16) {
        float4 v = *(const float4*)&h[n * 64 + q * 4];
        a0 += v.x; a1 += v.y; a2 += v.z; a3 += v.w;
    }
    a0 += __shfl_xor(a0, 16, 64); a0 += __shfl_xor(a0, 32, 64);
    a1 += __shfl_xor(a1, 16, 64); a1 += __shfl_xor(a1, 32, 64);
    a2 += __shfl_xor(a2, 16, 64); a2 += __shfl_xor(a2, 32, 64);
    a3 += __shfl_xor(a3, 16, 64); a3 += __shfl_xor(a3, 32, 64);
    if (lane < 16) {
        sums[w][4 * lane + 0] = a0;
        sums[w][4 * lane + 1] = a1;
        sums[w][4 * lane + 2] = a2;
        sums[w][4 * lane + 3] = a3;
    }
    __syncthreads();
    if (t < 64) {
        float tot = sums[0][t] + sums[1][t] + sums[2][t] + sums[3][t];
        float v = tot * Wfc[t];
#pragma unroll
        for (int off = 32; off; off >>= 1) v += __shfl_down(v, off, 64);
        if (t == 0) {
            float cnt = fmaxf((float)(s1 - s0), 1.0f);
            float z = v / cnt + bfc[0];
            out[g] = 1.0f / (1.0f + expf(-z));
        }
    }
}

extern "C" void kernel_launch(void* const* d_in, const int* in_sizes, int n_in,
                              void* d_out, int out_size, void* d_ws, size_t ws_size,
                              hipStream_t stream) {
    const float* x     = (const float*)d_in[0];
    const int*   edge  = (const int*)d_in[1];
    const int*   batch = (const int*)d_in[2];
    const float* W0 = (const float*)d_in[3];
    const float* b0 = (const float*)d_in[4];
    const float* W1 = (const float*)d_in[5];
    const float* b1 = (const float*)d_in[6];
    const float* W2 = (const float*)d_in[7];
    const float* b2 = (const float*)d_in[8];
    const float* W3 = (const float*)d_in[9];
    const float* b3 = (const float*)d_in[10];
    const float* Wfc = (const float*)d_in[11];
    const float* bfc = (const float*)d_in[12];
    float* out = (float*)d_out;

    const int E = in_sizes[1] / 2;
    const int* src = edge;
    const int* dst = edge + E;

    // workspace layout
    char* ws = (char*)d_ws;
    float* dsq    = (float*)ws;                   ws += sizeof(float) * N_NODES;
    int*   rowptr = (int*)ws;                     ws += sizeof(int) * (N_NODES + 1);
    int*   bcnt   = (int*)ws;                     ws += sizeof(int) * 256;
    int*   bstart = (int*)ws;                     ws += sizeof(int) * 256;
    int*   bcursor= (int*)ws;                     ws += sizeof(int) * 256;
    int*   gstart = (int*)ws;                     ws += sizeof(int) * (N_GRAPHS + 1);
    ws = (char*)(((size_t)ws + 15) & ~(size_t)15);
    uint*  xp2    = (uint*)ws;                    ws += sizeof(uint) * N_NODES * 8;
    int*   csr    = (int*)ws;                     ws += sizeof(int) * E;
    uint*  bufA   = (uint*)ws;                    ws += sizeof(uint) * N_NODES * 16;
    uint*  bufB   = (uint*)ws;                    ws += sizeof(uint) * N_NODES * 16;
    uint*  aggw   = (uint*)ws;                    ws += sizeof(uint) * N_NODES * 32;
    float* bufF   = (float*)ws;                   ws += sizeof(float) * N_NODES * EMB;
    uint*  sp     = (uint*)bufF;   // packed sorted pairs alias bufF (dead until layer 3)

    // ---- bucket sort + fused CSR build ----
    k_zero_i<<<1, 256, 0, stream>>>(bcnt, 256);
    k_bhist<<<512, 256, 0, stream>>>(dst, E, bcnt);
    k_bscan<<<1, 64, 0, stream>>>(bcnt, bstart, bcursor);
    k_bscatter<<<(E + CHUNK_E - 1) / CHUNK_E, 256, 0, stream>>>(src, dst, E, bcursor, sp);
    k_csr<<<NBKT, 512, 0, stream>>>(sp, bstart, rowptr, dsq, csr);
    k_gbound<<<(N_NODES + 255) / 256, 256, 0, stream>>>(batch, gstart);
    k_xprep2<<<512, 256, 0, stream>>>(x, dsq, xp2);

    // ---- 4 GCN layers (layer 0 fused; layers 1-3 split agg/mm) ----
    const int NBLK = N_NODES / 4;     // 25000 node-groups
    const int MGRID = N_NODES / 16;   // 6250 blocks for streaming matmul
    k_layer12<<<NBLK, 256, 0, stream>>>(rowptr, csr, dsq, (const uint2*)xp2, W0, b0, bufA);

    k_agg<<<NBLK, 256, 0, stream>>>(rowptr, csr, dsq, (const uint2*)bufA, aggw);
    k_mmact<0, 0><<<MGRID, 256, 0, stream>>>(dsq, aggw, W1, b1, bufB, nullptr);

    k_agg<<<NBLK, 256, 0, stream>>>(rowptr, csr, dsq, (const uint2*)bufB, aggw);
    k_mmact<0, 0><<<MGRID, 256, 0, stream>>>(dsq, aggw, W2, b2, bufA, nullptr);

    k_agg<<<NBLK, 256, 0, stream>>>(rowptr, csr, dsq, (const uint2*)bufA, aggw);
    k_mmact<1, 1><<<MGRID, 256, 0, stream>>>(dsq, aggw, W3, b3, nullptr, bufF);

    // ---- fused mean pool + fc + sigmoid ----
    k_poolfc<<<N_GRAPHS, 256, 0, stream>>>(bufF, gstart, Wfc, bfc, out);
}

// Round 20
// 364.425 us; speedup vs baseline: 1.0846x; 1.0846x over previous
//
#include <hip/hip_runtime.h>
#include <math.h>

#define N_NODES 100000
#define N_GRAPHS 512
#define EMB 64
#define NBKT 196         // ceil(100000 / 512) buckets of 512 nodes
#define BSH 9            // bucket shift (512 nodes)
#define CHUNK_E 4096     // edges per k_bscatter block

typedef unsigned int uint;
typedef __fp16 half_t;
typedef half_t h2_t __attribute__((ext_vector_type(2)));

__device__ __forceinline__ h2_t uint_as_h2(uint u) {
    union { uint u; h2_t h; } c; c.u = u; return c.h;
}
__device__ __forceinline__ uint h2_as_uint(h2_t h) {
    union { uint u; h2_t h; } c; c.h = h; return c.u;
}
__device__ __forceinline__ uint packh2(float a, float b) {
    return h2_as_uint(__builtin_amdgcn_cvt_pkrtz(a, b));
}

#if __has_builtin(__builtin_amdgcn_fdot2)
#define FDOT2(a, b, c) __builtin_amdgcn_fdot2((a), (b), (c), false)
#else
__device__ __forceinline__ float FDOT2(h2_t a, h2_t b, float c) {
    return c + (float)a[0] * (float)b[0] + (float)a[1] * (float)b[1];
}
#endif

// ---------------- bf16 pack/unpack ----------------
__device__ __forceinline__ float bflo(uint u) { return __uint_as_float(u << 16); }
__device__ __forceinline__ float bfhi(uint u) { return __uint_as_float(u & 0xffff0000u); }
__device__ __forceinline__ uint rne16(float f) {
    uint u = __float_as_uint(f);
    return (u + 0x7fffu + ((u >> 16) & 1u)) >> 16;
}
__device__ __forceinline__ uint pack2(float a, float b) {
    return rne16(a) | (rne16(b) << 16);
}

// ---------------- utility ----------------
__global__ void k_zero_i(int* __restrict__ p, int n) {
    int i = blockIdx.x * blockDim.x + threadIdx.x;
    int stride = gridDim.x * blockDim.x;
    for (; i < n; i += stride) p[i] = 0;
}

// bucket histogram of dst>>BSH, LDS-staged
__global__ __launch_bounds__(256) void k_bhist(const int* __restrict__ dst, int E,
                                               int* __restrict__ bcnt) {
    __shared__ int w[NBKT];
    for (int i = threadIdx.x; i < NBKT; i += 256) w[i] = 0;
    __syncthreads();
    int i = blockIdx.x * 256 + threadIdx.x;
    int stride = gridDim.x * 256;
    for (; i < E; i += stride) atomicAdd(&w[dst[i] >> BSH], 1);
    __syncthreads();
    for (int t = threadIdx.x; t < NBKT; t += 256)
        if (w[t]) atomicAdd(&bcnt[t], w[t]);
}

__global__ void k_bscan(const int* __restrict__ bcnt, int* __restrict__ bstart,
                        int* __restrict__ bcursor) {
    if (blockIdx.x == 0 && threadIdx.x == 0) {
        int run = 0;
        for (int b = 0; b < NBKT; ++b) { bstart[b] = run; bcursor[b] = run; run += bcnt[b]; }
        bstart[NBKT] = run;
    }
}

// counting-sort pass: partition edges into dst-buckets with LDS staging so
// global writes are coalesced per-bucket runs.
// sp[pos] = (src << 9) | (dst & 511)   (26 bits used)
__global__ __launch_bounds__(256) void k_bscatter(
    const int* __restrict__ src, const int* __restrict__ dst, int E,
    int* __restrict__ bcursor, uint* __restrict__ sp) {
    __shared__ int wcnt[NBKT];
    __shared__ int wbase[NBKT];
    __shared__ int lofs[NBKT];
    __shared__ int lcur[NBKT];
    __shared__ uint stage[CHUNK_E];
    __shared__ short sbkt[CHUNK_E];

    int e0 = blockIdx.x * CHUNK_E;
    int e1 = e0 + CHUNK_E;
    if (e1 > E) e1 = E;
    int t = threadIdx.x;

    for (int i = t; i < NBKT; i += 256) { wcnt[i] = 0; lcur[i] = 0; }
    __syncthreads();
    for (int i = e0 + t; i < e1; i += 256) atomicAdd(&wcnt[dst[i] >> BSH], 1);
    __syncthreads();
    if (t < NBKT) wbase[t] = atomicAdd(&bcursor[t], wcnt[t]);
    if (t == 0) {
        int run = 0;
        for (int b = 0; b < NBKT; ++b) { lofs[b] = run; run += wcnt[b]; }
    }
    __syncthreads();
    for (int i = e0 + t; i < e1; i += 256) {
        int d = dst[i];
        int b = d >> BSH;
        int l = lofs[b] + atomicAdd(&lcur[b], 1);
        stage[l] = ((uint)src[i] << BSH) | (uint)(d & 511);
        sbkt[l] = (short)b;
    }
    __syncthreads();
    int n = e1 - e0;
    for (int k = t; k < n; k += 256) {
        int b = sbkt[k];
        sp[wbase[b] + (k - lofs[b])] = stage[k];
    }
}

// fused CSR finalize, one block per 512-node bucket, 1 thread per node:
// LDS histogram -> shuffle scan (bucket base = bstart[b]) -> rowptr/dsq -> scatter
__global__ __launch_bounds__(512) void k_csr(const uint* __restrict__ sp,
                                             const int* __restrict__ bstart,
                                             int* __restrict__ rowptr,
                                             float* __restrict__ dsq,
                                             int* __restrict__ csr) {
    __shared__ int lcnt[512];
    __shared__ int wsum[8];
    int b = blockIdx.x, base = b << BSH, t = threadIdx.x;
    lcnt[t] = 0;
    __syncthreads();
    int s0 = bstart[b], s1 = bstart[b + 1];
    for (int i = s0 + t; i < s1; i += 512) atomicAdd(&lcnt[sp[i] & 511u], 1);
    __syncthreads();
    int c = lcnt[t];
    int lane = t & 63, wid = t >> 6;
    int inc = c;
    for (int off = 1; off < 64; off <<= 1) {
        int v = __shfl_up(inc, off, 64);
        if (lane >= off) inc += v;
    }
    if (lane == 63) wsum[wid] = inc;
    __syncthreads();
    int wbase = 0;
    for (int w = 0; w < wid; ++w) wbase += wsum[w];
    int p = s0 + wbase + inc - c;
    int n = base + t;
    lcnt[t] = p;    // becomes this node's scatter cursor
    if (n < N_NODES) { rowptr[n] = p; dsq[n] = rsqrtf((float)c + 1.0f); }
    if (b == NBKT - 1 && t == 511) rowptr[N_NODES] = s1;
    __syncthreads();
    for (int i = s0 + t; i < s1; i += 512) {
        uint pr = sp[i];
        int pos = atomicAdd(&lcnt[pr & 511u], 1);
        csr[pos] = (int)(pr >> BSH);
    }
}

// graph boundary detection on sorted batch index -> gstart[0..N_GRAPHS]
__global__ void k_gbound(const int* __restrict__ batch, int* __restrict__ gstart) {
    int i = blockIdx.x * blockDim.x + threadIdx.x;
    if (i >= N_NODES) return;
    int b = batch[i];
    if (i == 0) {
        for (int g = 0; g <= b; ++g) gstart[g] = 0;
    } else {
        int pb = batch[i - 1];
        for (int g = pb + 1; g <= b; ++g) gstart[g] = i;
    }
    if (i == N_NODES - 1) {
        for (int g = b + 1; g <= N_GRAPHS; ++g) gstart[g] = N_NODES;
    }
}

// xp2 = packed bf16 of dsq[n]*x, padded to 16 channels (8 uints / 4 uint2 per node)
__global__ void k_xprep2(const float* __restrict__ x, const float* __restrict__ dsq,
                         uint* __restrict__ xp2) {
    int i = blockIdx.x * blockDim.x + threadIdx.x;
    int stride = gridDim.x * blockDim.x;
    const int total = N_NODES * 8;
    for (; i < total; i += stride) {
        int n = i >> 3, u = i & 7;
        int c0 = 2 * u, c1 = c0 + 1;
        float d = dsq[n];
        float v0 = (c0 < 12) ? x[n * 12 + c0] * d : 0.0f;
        float v1 = (c1 < 12) ? x[n * 12 + c1] * d : 0.0f;
        xp2[i] = pack2(v0, v1);
    }
}

// fp8 epilogue pack: lane holds channel `lane` value sv (already x16 scaled);
// produces one uint per 4 lanes.
__device__ __forceinline__ void store_fp8_row(uint* __restrict__ hout, int node,
                                              int lane, float sv) {
    float pv = __shfl_xor(sv, 1, 64);
    uint w = (uint)__builtin_amdgcn_cvt_pk_fp8_f32(sv, pv, 0, false);
    uint w2 = __shfl_xor(w, 2, 64);
    if ((lane & 3) == 0) hout[node * 16 + (lane >> 2)] = (w & 0xffffu) | (w2 << 16);
}

// pure gather+reduce: fp8 rows in, f16 aggregated row out (128B coalesced).
// 4 loads in flight per 32-edge group (empirically optimal vs 8-deep).
__global__ __launch_bounds__(256) void k_agg(
    const int* __restrict__ rowptr, const int* __restrict__ csr,
    const float* __restrict__ dsq, const uint2* __restrict__ hin,
    uint* __restrict__ aggout) {
    int wid = threadIdx.x >> 6;
    int lane = threadIdx.x & 63;
    int q = lane >> 3;       // edge slot 0..7
    int cc = lane & 7;       // uint2 index in row -> channels 8cc..8cc+7

    int node = blockIdx.x * 4 + wid;
    int start = rowptr[node], end = rowptr[node + 1];
    float dn = dsq[node];

    float a0 = 0.0f, a1 = 0.0f, a2 = 0.0f, a3 = 0.0f;
    float a4 = 0.0f, a5 = 0.0f, a6 = 0.0f, a7 = 0.0f;
#define ACCU(u) do { \
        auto f0 = __builtin_amdgcn_cvt_pk_f32_fp8(u.x, false); \
        auto f1 = __builtin_amdgcn_cvt_pk_f32_fp8(u.x, true);  \
        auto f2 = __builtin_amdgcn_cvt_pk_f32_fp8(u.y, false); \
        auto f3 = __builtin_amdgcn_cvt_pk_f32_fp8(u.y, true);  \
        a0 += f0[0]; a1 += f0[1]; a2 += f1[0]; a3 += f1[1]; \
        a4 += f2[0]; a5 += f2[1]; a6 += f3[0]; a7 += f3[1]; } while (0)

    if (q == 0) {
        uint2 u = hin[node * 8 + cc];       // self-loop
        ACCU(u);
    }

    for (int k0 = start; k0 < end; k0 += 64) {
        int idx = k0 + lane;
        int s = (idx < end) ? csr[idx] : 0;
        int nk = end - k0; if (nk > 64) nk = 64;
        for (int jj = 0; jj < nk; jj += 32) {
            int e0 = jj + q, e1 = jj + 8 + q, e2 = jj + 16 + q, e3 = jj + 24 + q;
            int s0 = __shfl(s, e0, 64);
            int s1 = __shfl(s, e1, 64);
            int s2 = __shfl(s, e2, 64);
            int s3 = __shfl(s, e3, 64);
            uint2 u0 = make_uint2(0u, 0u), u1 = make_uint2(0u, 0u);
            uint2 u2 = make_uint2(0u, 0u), u3 = make_uint2(0u, 0u);
            if (e0 < nk) u0 = hin[s0 * 8 + cc];
            if (e1 < nk) u1 = hin[s1 * 8 + cc];
            if (e2 < nk) u2 = hin[s2 * 8 + cc];
            if (e3 < nk) u3 = hin[s3 * 8 + cc];
            ACCU(u0); ACCU(u1); ACCU(u2); ACCU(u3);
        }
    }
#undef ACCU
#define RED(a) a += __shfl_xor(a, 8, 64); a += __shfl_xor(a, 16, 64); a += __shfl_xor(a, 32, 64)
    RED(a0); RED(a1); RED(a2); RED(a3); RED(a4); RED(a5); RED(a6); RED(a7);
#undef RED
    if (q == 0) {
        float g = dn * (1.0f / 16.0f);
        uint4 pk;
        pk.x = packh2(g * a0, g * a1);
        pk.y = packh2(g * a2, g * a3);
        pk.z = packh2(g * a4, g * a5);
        pk.w = packh2(g * a6, g * a7);
        *(uint4*)&aggout[node * 32 + cc * 4] = pk;
    }
}

// streaming matmul + activation + fp8 pack: reads f16 agg rows, W in VGPRs.
// Grid-strided; occupancy-insensitive (stream-bound).
template <int ACT, int LAST>
__global__ __launch_bounds__(256) void k_mmact(
    const float* __restrict__ dsq, const uint* __restrict__ agg,
    const float* __restrict__ W, const float* __restrict__ b,
    uint* __restrict__ hout, float* __restrict__ houtf) {
    __shared__ uint rowsh[4][32];

    int wid = threadIdx.x >> 6;
    int lane = threadIdx.x & 63;

    uint wreg[32];
#pragma unroll
    for (int m = 0; m < 32; ++m)
        wreg[m] = packh2(W[(2 * m) * 64 + lane], W[(2 * m + 1) * 64 + lane]);
    float bias = b[lane];

    for (int grp = blockIdx.x; grp < N_NODES / 4; grp += gridDim.x) {
        int node = grp * 4 + wid;
        // coalesced 128B row load: lanes 0..31 load one uint each
        if (lane < 32) rowsh[wid][lane] = agg[node * 32 + lane];
        // same-wave producer/consumer: LDS ops in-order, no barrier needed

        float sacc = bias;
#pragma unroll
        for (int j = 0; j < 8; ++j) {
            uint4 r = *(const uint4*)&rowsh[wid][4 * j];
            sacc = FDOT2(uint_as_h2(r.x), uint_as_h2(wreg[4 * j + 0]), sacc);
            sacc = FDOT2(uint_as_h2(r.y), uint_as_h2(wreg[4 * j + 1]), sacc);
            sacc = FDOT2(uint_as_h2(r.z), uint_as_h2(wreg[4 * j + 2]), sacc);
            sacc = FDOT2(uint_as_h2(r.w), uint_as_h2(wreg[4 * j + 3]), sacc);
        }
        float val = ACT ? fmaxf(sacc, 0.0f) : (sacc > 0.0f ? sacc : 0.01f * sacc);

        if (LAST) {
            houtf[node * 64 + lane] = val;
        } else {
            store_fp8_row(hout, node, lane, 16.0f * dsq[node] * val);
        }
    }
}

// layer 0: pull-aggregate bf16 xp2 (16-ch padded, uint2, 16 edge-slots,
// 4 loads in flight = 64 edges/iter) + 12x64 matmul + leaky, fp8 packed out
__global__ __launch_bounds__(256) void k_layer12(
    const int* __restrict__ rowptr, const int* __restrict__ csr,
    const float* __restrict__ dsq, const uint2* __restrict__ xp2,
    const float* __restrict__ W, const float* __restrict__ b,
    uint* __restrict__ hout) {
    __shared__ float Wl[12 * 64];
    __shared__ float rows[4][16];
    for (int i = threadIdx.x; i < 12 * 64; i += 256) Wl[i] = W[i];

    int wid = threadIdx.x >> 6;
    int lane = threadIdx.x & 63;
    int node = blockIdx.x * 4 + wid;
    int q = lane >> 2;       // edge slot 0..15
    int cc = lane & 3;       // uint2 index -> channels 4cc..4cc+3 (of 16)

    int start = rowptr[node], end = rowptr[node + 1];
    float dn = dsq[node];

    float a0 = 0.0f, a1 = 0.0f, a2 = 0.0f, a3 = 0.0f;
    if (q == 0) {
        uint2 u = xp2[node * 4 + cc];
        a0 = bflo(u.x); a1 = bfhi(u.x); a2 = bflo(u.y); a3 = bfhi(u.y);
    }

    for (int k0 = start; k0 < end; k0 += 64) {
        int idx = k0 + lane;
        int s = (idx < end) ? csr[idx] : 0;
        int nk = end - k0; if (nk > 64) nk = 64;
        int s0 = __shfl(s, q, 64);
        int s1 = __shfl(s, 16 + q, 64);
        int s2 = __shfl(s, 32 + q, 64);
        int s3 = __shfl(s, 48 + q, 64);
        uint2 u0 = make_uint2(0u, 0u), u1 = make_uint2(0u, 0u);
        uint2 u2 = make_uint2(0u, 0u), u3 = make_uint2(0u, 0u);
        if (q < nk)      u0 = xp2[s0 * 4 + cc];
        if (16 + q < nk) u1 = xp2[s1 * 4 + cc];
        if (32 + q < nk) u2 = xp2[s2 * 4 + cc];
        if (48 + q < nk) u3 = xp2[s3 * 4 + cc];
        a0 += bflo(u0.x); a1 += bfhi(u0.x); a2 += bflo(u0.y); a3 += bfhi(u0.y);
        a0 += bflo(u1.x); a1 += bfhi(u1.x); a2 += bflo(u1.y); a3 += bfhi(u1.y);
        a0 += bflo(u2.x); a1 += bfhi(u2.x); a2 += bflo(u2.y); a3 += bfhi(u2.y);
        a0 += bflo(u3.x); a1 += bfhi(u3.x); a2 += bflo(u3.y); a3 += bfhi(u3.y);
    }
    a0 += __shfl_xor(a0, 4, 64); a0 += __shfl_xor(a0, 8, 64);
    a0 += __shfl_xor(a0, 16, 64); a0 += __shfl_xor(a0, 32, 64);
    a1 += __shfl_xor(a1, 4, 64); a1 += __shfl_xor(a1, 8, 64);
    a1 += __shfl_xor(a1, 16, 64); a1 += __shfl_xor(a1, 32, 64);
    a2 += __shfl_xor(a2, 4, 64); a2 += __shfl_xor(a2, 8, 64);
    a2 += __shfl_xor(a2, 16, 64); a2 += __shfl_xor(a2, 32, 64);
    a3 += __shfl_xor(a3, 4, 64); a3 += __shfl_xor(a3, 8, 64);
    a3 += __shfl_xor(a3, 16, 64); a3 += __shfl_xor(a3, 32, 64);
    if (q == 0) {
        rows[wid][4 * cc + 0] = dn * a0;
        rows[wid][4 * cc + 1] = dn * a1;
        rows[wid][4 * cc + 2] = dn * a2;
        rows[wid][4 * cc + 3] = dn * a3;
    }
    __syncthreads();

    float sacc = b[lane];
#pragma unroll
    for (int k = 0; k < 12; ++k) sacc += rows[wid][k] * Wl[k * 64 + lane];
    float val = (sacc > 0.0f) ? sacc : 0.01f * sacc;
    store_fp8_row(hout, node, lane, 16.0f * dn * val);
}

// fused mean-pool + FC + sigmoid: one block per graph, float4 loads,
// no atomics (range from gstart)
__global__ __launch_bounds__(256) void k_poolfc(
    const float* __restrict__ h, const int* __restrict__ gstart,
    const float* __restrict__ Wfc, const float* __restrict__ bfc,
    float* __restrict__ out) {
    __shared__ float sums[4][64];
    int g = blockIdx.x;
    int t = threadIdx.x;
    int w = t >> 6, lane = t & 63;
    int q = lane & 15, sub = lane >> 4;
    int s0 = gstart[g], s1 = gstart[g + 1];

    float a0 = 0.0f, a1 = 0.0f, a2 = 0.0f, a3 = 0.0f;
    for (int n = s0 + w * 4 + sub; n < s1; n += 16) {
        float4 v = *(const float4*)&h[n * 64 + q * 4];
        a0 += v.x; a1 += v.y; a2 += v.z; a3 += v.w;
    }
    a0 += __shfl_xor(a0, 16, 64); a0 += __shfl_xor(a0, 32, 64);
    a1 += __shfl_xor(a1, 16, 64); a1 += __shfl_xor(a1, 32, 64);
    a2 += __shfl_xor(a2, 16, 64); a2 += __shfl_xor(a2, 32, 64);
    a3 += __shfl_xor(a3, 16, 64); a3 += __shfl_xor(a3, 32, 64);
    if (lane < 16) {
        sums[w][4 * lane + 0] = a0;
        sums[w][4 * lane + 1] = a1;
        sums[w][4 * lane + 2] = a2;
        sums[w][4 * lane + 3] = a3;
    }
    __syncthreads();
    if (t < 64) {
        float tot = sums[0][t] + sums[1][t] + sums[2][t] + sums[3][t];
        float v = tot * Wfc[t];
#pragma unroll
        for (int off = 32; off; off >>= 1) v += __shfl_down(v, off, 64);
        if (t == 0) {
            float cnt = fmaxf((float)(s1 - s0), 1.0f);
            float z = v / cnt + bfc[0];
            out[g] = 1.0f / (1.0f + expf(-z));
        }
    }
}

extern "C" void kernel_launch(void* const* d_in, const int* in_sizes, int n_in,
                              void* d_out, int out_size, void* d_ws, size_t ws_size,
                              hipStream_t stream) {
    const float* x     = (const float*)d_in[0];
    const int*   edge  = (const int*)d_in[1];
    const int*   batch = (const int*)d_in[2];
    const float* W0 = (const float*)d_in[3];
    const float* b0 = (const float*)d_in[4];
    const float* W1 = (const float*)d_in[5];
    const float* b1 = (const float*)d_in[6];
    const float* W2 = (const float*)d_in[7];
    const float* b2 = (const float*)d_in[8];
    const float* W3 = (const float*)d_in[9];
    const float* b3 = (const float*)d_in[10];
    const float* Wfc = (const float*)d_in[11];
    const float* bfc = (const float*)d_in[12];
    float* out = (float*)d_out;

    const int E = in_sizes[1] / 2;
    const int* src = edge;
    const int* dst = edge + E;

    // workspace layout
    char* ws = (char*)d_ws;
    float* dsq    = (float*)ws;                   ws += sizeof(float) * N_NODES;
    int*   rowptr = (int*)ws;                     ws += sizeof(int) * (N_NODES + 1);
    int*   bcnt   = (int*)ws;                     ws += sizeof(int) * 256;
    int*   bstart = (int*)ws;                     ws += sizeof(int) * 256;
    int*   bcursor= (int*)ws;                     ws += sizeof(int) * 256;
    int*   gstart = (int*)ws;                     ws += sizeof(int) * (N_GRAPHS + 1);
    ws = (char*)(((size_t)ws + 15) & ~(size_t)15);
    uint*  xp2    = (uint*)ws;                    ws += sizeof(uint) * N_NODES * 8;
    int*   csr    = (int*)ws;                     ws += sizeof(int) * E;
    uint*  bufA   = (uint*)ws;                    ws += sizeof(uint) * N_NODES * 16;
    uint*  bufB   = (uint*)ws;                    ws += sizeof(uint) * N_NODES * 16;
    uint*  aggw   = (uint*)ws;                    ws += sizeof(uint) * N_NODES * 32;
    float* bufF   = (float*)ws;                   ws += sizeof(float) * N_NODES * EMB;
    uint*  sp     = (uint*)bufF;   // packed sorted pairs alias bufF (dead until layer 3)

    // ---- bucket sort + fused CSR build ----
    k_zero_i<<<1, 256, 0, stream>>>(bcnt, 256);
    k_bhist<<<512, 256, 0, stream>>>(dst, E, bcnt);
    k_bscan<<<1, 64, 0, stream>>>(bcnt, bstart, bcursor);
    k_bscatter<<<(E + CHUNK_E - 1) / CHUNK_E, 256, 0, stream>>>(src, dst, E, bcursor, sp);
    k_csr<<<NBKT, 512, 0, stream>>>(sp, bstart, rowptr, dsq, csr);
    k_gbound<<<(N_NODES + 255) / 256, 256, 0, stream>>>(batch, gstart);
    k_xprep2<<<512, 256, 0, stream>>>(x, dsq, xp2);

    // ---- 4 GCN layers (layer 0 fused; layers 1-3 split agg/mm) ----
    const int NBLK = N_NODES / 4;     // 25000 node-groups
    const int MGRID = N_NODES / 16;   // 6250 blocks for streaming matmul
    k_layer12<<<NBLK, 256, 0, stream>>>(rowptr, csr, dsq, (const uint2*)xp2, W0, b0, bufA);

    k_agg<<<NBLK, 256, 0, stream>>>(rowptr, csr, dsq, (const uint2*)bufA, aggw);
    k_mmact<0, 0><<<MGRID, 256, 0, stream>>>(dsq, aggw, W1, b1, bufB, nullptr);

    k_agg<<<NBLK, 256, 0, stream>>>(rowptr, csr, dsq, (const uint2*)bufB, aggw);
    k_mmact<0, 0><<<MGRID, 256, 0, stream>>>(dsq, aggw, W2, b2, bufA, nullptr);

    k_agg<<<NBLK, 256, 0, stream>>>(rowptr, csr, dsq, (const uint2*)bufA, aggw);
    k_mmact<1, 1><<<MGRID, 256, 0, stream>>>(dsq, aggw, W3, b3, nullptr, bufF);

    // ---- fused mean pool + fc + sigmoid ----
    k_poolfc<<<N_GRAPHS, 256, 0, stream>>>(bufF, gstart, Wfc, bfc, out);
}

// Round 21
// 359.623 us; speedup vs baseline: 1.0990x; 1.0134x over previous
//
#include <hip/hip_runtime.h>
#include <math.h>

#define N_NODES 100000
#define N_GRAPHS 512
#define EMB 64
#define NBKT 196         // ceil(100000 / 512) buckets of 512 nodes
#define BSH 9            // bucket shift (512 nodes)
#define CHUNK_E 4096     // edges per k_bscatter block

typedef unsigned int uint;
typedef __fp16 half_t;
typedef half_t h2_t __attribute__((ext_vector_type(2)));

__device__ __forceinline__ h2_t uint_as_h2(uint u) {
    union { uint u; h2_t h; } c; c.u = u; return c.h;
}
__device__ __forceinline__ uint h2_as_uint(h2_t h) {
    union { uint u; h2_t h; } c; c.h = h; return c.u;
}
__device__ __forceinline__ uint packh2(float a, float b) {
    return h2_as_uint(__builtin_amdgcn_cvt_pkrtz(a, b));
}

#if __has_builtin(__builtin_amdgcn_fdot2)
#define FDOT2(a, b, c) __builtin_amdgcn_fdot2((a), (b), (c), false)
#else
__device__ __forceinline__ float FDOT2(h2_t a, h2_t b, float c) {
    return c + (float)a[0] * (float)b[0] + (float)a[1] * (float)b[1];
}
#endif

// ---------------- utility ----------------
__global__ void k_zero_i(int* __restrict__ p, int n) {
    int i = blockIdx.x * blockDim.x + threadIdx.x;
    int stride = gridDim.x * blockDim.x;
    for (; i < n; i += stride) p[i] = 0;
}

// bucket histogram of dst>>BSH, LDS-staged
__global__ __launch_bounds__(256) void k_bhist(const int* __restrict__ dst, int E,
                                               int* __restrict__ bcnt) {
    __shared__ int w[NBKT];
    for (int i = threadIdx.x; i < NBKT; i += 256) w[i] = 0;
    __syncthreads();
    int i = blockIdx.x * 256 + threadIdx.x;
    int stride = gridDim.x * 256;
    for (; i < E; i += stride) atomicAdd(&w[dst[i] >> BSH], 1);
    __syncthreads();
    for (int t = threadIdx.x; t < NBKT; t += 256)
        if (w[t]) atomicAdd(&bcnt[t], w[t]);
}

__global__ void k_bscan(const int* __restrict__ bcnt, int* __restrict__ bstart,
                        int* __restrict__ bcursor) {
    if (blockIdx.x == 0 && threadIdx.x == 0) {
        int run = 0;
        for (int b = 0; b < NBKT; ++b) { bstart[b] = run; bcursor[b] = run; run += bcnt[b]; }
        bstart[NBKT] = run;
    }
}

// counting-sort pass: partition edges into dst-buckets with LDS staging so
// global writes are coalesced per-bucket runs.
// sp[pos] = (src << 9) | (dst & 511)   (26 bits used)
__global__ __launch_bounds__(256) void k_bscatter(
    const int* __restrict__ src, const int* __restrict__ dst, int E,
    int* __restrict__ bcursor, uint* __restrict__ sp) {
    __shared__ int wcnt[NBKT];
    __shared__ int wbase[NBKT];
    __shared__ int lofs[NBKT];
    __shared__ int lcur[NBKT];
    __shared__ uint stage[CHUNK_E];
    __shared__ short sbkt[CHUNK_E];

    int e0 = blockIdx.x * CHUNK_E;
    int e1 = e0 + CHUNK_E;
    if (e1 > E) e1 = E;
    int t = threadIdx.x;

    for (int i = t; i < NBKT; i += 256) { wcnt[i] = 0; lcur[i] = 0; }
    __syncthreads();
    for (int i = e0 + t; i < e1; i += 256) atomicAdd(&wcnt[dst[i] >> BSH], 1);
    __syncthreads();
    if (t < NBKT) wbase[t] = atomicAdd(&bcursor[t], wcnt[t]);
    if (t == 0) {
        int run = 0;
        for (int b = 0; b < NBKT; ++b) { lofs[b] = run; run += wcnt[b]; }
    }
    __syncthreads();
    for (int i = e0 + t; i < e1; i += 256) {
        int d = dst[i];
        int b = d >> BSH;
        int l = lofs[b] + atomicAdd(&lcur[b], 1);
        stage[l] = ((uint)src[i] << BSH) | (uint)(d & 511);
        sbkt[l] = (short)b;
    }
    __syncthreads();
    int n = e1 - e0;
    for (int k = t; k < n; k += 256) {
        int b = sbkt[k];
        sp[wbase[b] + (k - lofs[b])] = stage[k];
    }
}

// fused CSR finalize, one block per 512-node bucket, 1 thread per node:
// LDS histogram -> shuffle scan (bucket base = bstart[b]) -> rowptr/dsq -> scatter
__global__ __launch_bounds__(512) void k_csr(const uint* __restrict__ sp,
                                             const int* __restrict__ bstart,
                                             int* __restrict__ rowptr,
                                             float* __restrict__ dsq,
                                             int* __restrict__ csr) {
    __shared__ int lcnt[512];
    __shared__ int wsum[8];
    int b = blockIdx.x, base = b << BSH, t = threadIdx.x;
    lcnt[t] = 0;
    __syncthreads();
    int s0 = bstart[b], s1 = bstart[b + 1];
    for (int i = s0 + t; i < s1; i += 512) atomicAdd(&lcnt[sp[i] & 511u], 1);
    __syncthreads();
    int c = lcnt[t];
    int lane = t & 63, wid = t >> 6;
    int inc = c;
    for (int off = 1; off < 64; off <<= 1) {
        int v = __shfl_up(inc, off, 64);
        if (lane >= off) inc += v;
    }
    if (lane == 63) wsum[wid] = inc;
    __syncthreads();
    int wbase = 0;
    for (int w = 0; w < wid; ++w) wbase += wsum[w];
    int p = s0 + wbase + inc - c;
    int n = base + t;
    lcnt[t] = p;    // becomes this node's scatter cursor
    if (n < N_NODES) { rowptr[n] = p; dsq[n] = rsqrtf((float)c + 1.0f); }
    if (b == NBKT - 1 && t == 511) rowptr[N_NODES] = s1;
    __syncthreads();
    for (int i = s0 + t; i < s1; i += 512) {
        uint pr = sp[i];
        int pos = atomicAdd(&lcnt[pr & 511u], 1);
        csr[pos] = (int)(pr >> BSH);
    }
}

// graph boundary detection on sorted batch index -> gstart[0..N_GRAPHS]
__global__ void k_gbound(const int* __restrict__ batch, int* __restrict__ gstart) {
    int i = blockIdx.x * blockDim.x + threadIdx.x;
    if (i >= N_NODES) return;
    int b = batch[i];
    if (i == 0) {
        for (int g = 0; g <= b; ++g) gstart[g] = 0;
    } else {
        int pb = batch[i - 1];
        for (int g = pb + 1; g <= b; ++g) gstart[g] = i;
    }
    if (i == N_NODES - 1) {
        for (int g = b + 1; g <= N_GRAPHS; ++g) gstart[g] = N_NODES;
    }
}

// xp3 = fp8 of 16*dsq[n]*x, padded to 16 channels (4 uints per node, 16B/row)
__global__ void k_xprep3(const float* __restrict__ x, const float* __restrict__ dsq,
                         uint* __restrict__ xp3) {
    int i = blockIdx.x * blockDim.x + threadIdx.x;
    int stride = gridDim.x * blockDim.x;
    const int total = N_NODES * 4;
    for (; i < total; i += stride) {
        int n = i >> 2, u = i & 3;
        int c0 = 4 * u;
        float d = 16.0f * dsq[n];
        float v0 = (c0     < 12) ? x[n * 12 + c0    ] * d : 0.0f;
        float v1 = (c0 + 1 < 12) ? x[n * 12 + c0 + 1] * d : 0.0f;
        float v2 = (c0 + 2 < 12) ? x[n * 12 + c0 + 2] * d : 0.0f;
        float v3 = (c0 + 3 < 12) ? x[n * 12 + c0 + 3] * d : 0.0f;
        uint wlo = (uint)__builtin_amdgcn_cvt_pk_fp8_f32(v0, v1, 0, false) & 0xffffu;
        uint whi = (uint)__builtin_amdgcn_cvt_pk_fp8_f32(v2, v3, 0, false) & 0xffffu;
        xp3[i] = wlo | (whi << 16);
    }
}

// fp8 epilogue pack: lane holds channel `lane` value sv (already x16 scaled);
// produces one uint per 4 lanes.
__device__ __forceinline__ void store_fp8_row(uint* __restrict__ hout, int node,
                                              int lane, float sv) {
    float pv = __shfl_xor(sv, 1, 64);
    uint w = (uint)__builtin_amdgcn_cvt_pk_fp8_f32(sv, pv, 0, false);
    uint w2 = __shfl_xor(w, 2, 64);
    if ((lane & 3) == 0) hout[node * 16 + (lane >> 2)] = (w & 0xffffu) | (w2 << 16);
}

// pure gather+reduce: fp8 rows in, f16 aggregated row out (128B coalesced).
// 4 loads in flight per 32-edge group (empirically optimal vs 8-deep).
__global__ __launch_bounds__(256) void k_agg(
    const int* __restrict__ rowptr, const int* __restrict__ csr,
    const float* __restrict__ dsq, const uint2* __restrict__ hin,
    uint* __restrict__ aggout) {
    int wid = threadIdx.x >> 6;
    int lane = threadIdx.x & 63;
    int q = lane >> 3;       // edge slot 0..7
    int cc = lane & 7;       // uint2 index in row -> channels 8cc..8cc+7

    int node = blockIdx.x * 4 + wid;
    int start = rowptr[node], end = rowptr[node + 1];
    float dn = dsq[node];

    float a0 = 0.0f, a1 = 0.0f, a2 = 0.0f, a3 = 0.0f;
    float a4 = 0.0f, a5 = 0.0f, a6 = 0.0f, a7 = 0.0f;
#define ACCU(u) do { \
        auto f0 = __builtin_amdgcn_cvt_pk_f32_fp8(u.x, false); \
        auto f1 = __builtin_amdgcn_cvt_pk_f32_fp8(u.x, true);  \
        auto f2 = __builtin_amdgcn_cvt_pk_f32_fp8(u.y, false); \
        auto f3 = __builtin_amdgcn_cvt_pk_f32_fp8(u.y, true);  \
        a0 += f0[0]; a1 += f0[1]; a2 += f1[0]; a3 += f1[1]; \
        a4 += f2[0]; a5 += f2[1]; a6 += f3[0]; a7 += f3[1]; } while (0)

    if (q == 0) {
        uint2 u = hin[node * 8 + cc];       // self-loop
        ACCU(u);
    }

    for (int k0 = start; k0 < end; k0 += 64) {
        int idx = k0 + lane;
        int s = (idx < end) ? csr[idx] : 0;
        int nk = end - k0; if (nk > 64) nk = 64;
        for (int jj = 0; jj < nk; jj += 32) {
            int e0 = jj + q, e1 = jj + 8 + q, e2 = jj + 16 + q, e3 = jj + 24 + q;
            int s0 = __shfl(s, e0, 64);
            int s1 = __shfl(s, e1, 64);
            int s2 = __shfl(s, e2, 64);
            int s3 = __shfl(s, e3, 64);
            uint2 u0 = make_uint2(0u, 0u), u1 = make_uint2(0u, 0u);
            uint2 u2 = make_uint2(0u, 0u), u3 = make_uint2(0u, 0u);
            if (e0 < nk) u0 = hin[s0 * 8 + cc];
            if (e1 < nk) u1 = hin[s1 * 8 + cc];
            if (e2 < nk) u2 = hin[s2 * 8 + cc];
            if (e3 < nk) u3 = hin[s3 * 8 + cc];
            ACCU(u0); ACCU(u1); ACCU(u2); ACCU(u3);
        }
    }
#undef ACCU
#define RED(a) a += __shfl_xor(a, 8, 64); a += __shfl_xor(a, 16, 64); a += __shfl_xor(a, 32, 64)
    RED(a0); RED(a1); RED(a2); RED(a3); RED(a4); RED(a5); RED(a6); RED(a7);
#undef RED
    if (q == 0) {
        float g = dn * (1.0f / 16.0f);
        uint4 pk;
        pk.x = packh2(g * a0, g * a1);
        pk.y = packh2(g * a2, g * a3);
        pk.z = packh2(g * a4, g * a5);
        pk.w = packh2(g * a6, g * a7);
        *(uint4*)&aggout[node * 32 + cc * 4] = pk;
    }
}

// streaming matmul + activation + fp8 pack: reads f16 agg rows, W in VGPRs.
// Few blocks (1024) so the per-block W preload is amortized ~24x.
template <int ACT, int LAST>
__global__ __launch_bounds__(256) void k_mmact(
    const float* __restrict__ dsq, const uint* __restrict__ agg,
    const float* __restrict__ W, const float* __restrict__ b,
    uint* __restrict__ hout, float* __restrict__ houtf) {
    __shared__ uint rowsh[4][32];

    int wid = threadIdx.x >> 6;
    int lane = threadIdx.x & 63;

    uint wreg[32];
#pragma unroll
    for (int m = 0; m < 32; ++m)
        wreg[m] = packh2(W[(2 * m) * 64 + lane], W[(2 * m + 1) * 64 + lane]);
    float bias = b[lane];

    for (int grp = blockIdx.x; grp < N_NODES / 4; grp += gridDim.x) {
        int node = grp * 4 + wid;
        // coalesced 128B row load: lanes 0..31 load one uint each
        if (lane < 32) rowsh[wid][lane] = agg[node * 32 + lane];
        // same-wave producer/consumer: LDS ops in-order, no barrier needed

        float sacc = bias;
#pragma unroll
        for (int j = 0; j < 8; ++j) {
            uint4 r = *(const uint4*)&rowsh[wid][4 * j];
            sacc = FDOT2(uint_as_h2(r.x), uint_as_h2(wreg[4 * j + 0]), sacc);
            sacc = FDOT2(uint_as_h2(r.y), uint_as_h2(wreg[4 * j + 1]), sacc);
            sacc = FDOT2(uint_as_h2(r.z), uint_as_h2(wreg[4 * j + 2]), sacc);
            sacc = FDOT2(uint_as_h2(r.w), uint_as_h2(wreg[4 * j + 3]), sacc);
        }
        float val = ACT ? fmaxf(sacc, 0.0f) : (sacc > 0.0f ? sacc : 0.01f * sacc);

        if (LAST) {
            houtf[node * 64 + lane] = val;
        } else {
            store_fp8_row(hout, node, lane, 16.0f * dsq[node] * val);
        }
    }
}

// layer 0: pull-aggregate fp8 xp3 (16-ch padded, 16B/row, uint loads,
// 16 edge-slots x 4 loads in flight = 64 edges/iter) + 12x64 matmul + leaky,
// fp8 packed out. xp3 holds fp8(16*dsq*x); 1/16 folded into dn multiply.
__global__ __launch_bounds__(256) void k_layer12(
    const int* __restrict__ rowptr, const int* __restrict__ csr,
    const float* __restrict__ dsq, const uint* __restrict__ xp3,
    const float* __restrict__ W, const float* __restrict__ b,
    uint* __restrict__ hout) {
    __shared__ float Wl[12 * 64];
    __shared__ float rows[4][16];
    for (int i = threadIdx.x; i < 12 * 64; i += 256) Wl[i] = W[i];

    int wid = threadIdx.x >> 6;
    int lane = threadIdx.x & 63;
    int node = blockIdx.x * 4 + wid;
    int q = lane >> 2;       // edge slot 0..15
    int cc = lane & 3;       // uint index -> channels 4cc..4cc+3 (of 16)

    int start = rowptr[node], end = rowptr[node + 1];
    float dn = dsq[node];

    float a0 = 0.0f, a1 = 0.0f, a2 = 0.0f, a3 = 0.0f;
#define ACCU1(u) do { \
        auto f0 = __builtin_amdgcn_cvt_pk_f32_fp8(u, false); \
        auto f1 = __builtin_amdgcn_cvt_pk_f32_fp8(u, true);  \
        a0 += f0[0]; a1 += f0[1]; a2 += f1[0]; a3 += f1[1]; } while (0)

    if (q == 0) {
        uint u = xp3[node * 4 + cc];
        ACCU1(u);
    }

    for (int k0 = start; k0 < end; k0 += 64) {
        int idx = k0 + lane;
        int s = (idx < end) ? csr[idx] : 0;
        int nk = end - k0; if (nk > 64) nk = 64;
        int s0 = __shfl(s, q, 64);
        int s1 = __shfl(s, 16 + q, 64);
        int s2 = __shfl(s, 32 + q, 64);
        int s3 = __shfl(s, 48 + q, 64);
        uint u0 = 0u, u1 = 0u, u2 = 0u, u3 = 0u;
        if (q < nk)      u0 = xp3[s0 * 4 + cc];
        if (16 + q < nk) u1 = xp3[s1 * 4 + cc];
        if (32 + q < nk) u2 = xp3[s2 * 4 + cc];
        if (48 + q < nk) u3 = xp3[s3 * 4 + cc];
        ACCU1(u0); ACCU1(u1); ACCU1(u2); ACCU1(u3);
    }
#undef ACCU1
    a0 += __shfl_xor(a0, 4, 64); a0 += __shfl_xor(a0, 8, 64);
    a0 += __shfl_xor(a0, 16, 64); a0 += __shfl_xor(a0, 32, 64);
    a1 += __shfl_xor(a1, 4, 64); a1 += __shfl_xor(a1, 8, 64);
    a1 += __shfl_xor(a1, 16, 64); a1 += __shfl_xor(a1, 32, 64);
    a2 += __shfl_xor(a2, 4, 64); a2 += __shfl_xor(a2, 8, 64);
    a2 += __shfl_xor(a2, 16, 64); a2 += __shfl_xor(a2, 32, 64);
    a3 += __shfl_xor(a3, 4, 64); a3 += __shfl_xor(a3, 8, 64);
    a3 += __shfl_xor(a3, 16, 64); a3 += __shfl_xor(a3, 32, 64);
    if (q == 0) {
        float g = dn * (1.0f / 16.0f);
        rows[wid][4 * cc + 0] = g * a0;
        rows[wid][4 * cc + 1] = g * a1;
        rows[wid][4 * cc + 2] = g * a2;
        rows[wid][4 * cc + 3] = g * a3;
    }
    __syncthreads();

    float sacc = b[lane];
#pragma unroll
    for (int k = 0; k < 12; ++k) sacc += rows[wid][k] * Wl[k * 64 + lane];
    float val = (sacc > 0.0f) ? sacc : 0.01f * sacc;
    store_fp8_row(hout, node, lane, 16.0f * dn * val);
}

// fused mean-pool + FC + sigmoid: one block per graph, float4 loads,
// no atomics (range from gstart)
__global__ __launch_bounds__(256) void k_poolfc(
    const float* __restrict__ h, const int* __restrict__ gstart,
    const float* __restrict__ Wfc, const float* __restrict__ bfc,
    float* __restrict__ out) {
    __shared__ float sums[4][64];
    int g = blockIdx.x;
    int t = threadIdx.x;
    int w = t >> 6, lane = t & 63;
    int q = lane & 15, sub = lane >> 4;
    int s0 = gstart[g], s1 = gstart[g + 1];

    float a0 = 0.0f, a1 = 0.0f, a2 = 0.0f, a3 = 0.0f;
    for (int n = s0 + w * 4 + sub; n < s1; n += 16) {
        float4 v = *(const float4*)&h[n * 64 + q * 4];
        a0 += v.x; a1 += v.y; a2 += v.z; a3 += v.w;
    }
    a0 += __shfl_xor(a0, 16, 64); a0 += __shfl_xor(a0, 32, 64);
    a1 += __shfl_xor(a1, 16, 64); a1 += __shfl_xor(a1, 32, 64);
    a2 += __shfl_xor(a2, 16, 64); a2 += __shfl_xor(a2, 32, 64);
    a3 += __shfl_xor(a3, 16, 64); a3 += __shfl_xor(a3, 32, 64);
    if (lane < 16) {
        sums[w][4 * lane + 0] = a0;
        sums[w][4 * lane + 1] = a1;
        sums[w][4 * lane + 2] = a2;
        sums[w][4 * lane + 3] = a3;
    }
    __syncthreads();
    if (t < 64) {
        float tot = sums[0][t] + sums[1][t] + sums[2][t] + sums[3][t];
        float v = tot * Wfc[t];
#pragma unroll
        for (int off = 32; off; off >>= 1) v += __shfl_down(v, off, 64);
        if (t == 0) {
            float cnt = fmaxf((float)(s1 - s0), 1.0f);
            float z = v / cnt + bfc[0];
            out[g] = 1.0f / (1.0f + expf(-z));
        }
    }
}

extern "C" void kernel_launch(void* const* d_in, const int* in_sizes, int n_in,
                              void* d_out, int out_size, void* d_ws, size_t ws_size,
                              hipStream_t stream) {
    const float* x     = (const float*)d_in[0];
    const int*   edge  = (const int*)d_in[1];
    const int*   batch = (const int*)d_in[2];
    const float* W0 = (const float*)d_in[3];
    const float* b0 = (const float*)d_in[4];
    const float* W1 = (const float*)d_in[5];
    const float* b1 = (const float*)d_in[6];
    const float* W2 = (const float*)d_in[7];
    const float* b2 = (const float*)d_in[8];
    const float* W3 = (const float*)d_in[9];
    const float* b3 = (const float*)d_in[10];
    const float* Wfc = (const float*)d_in[11];
    const float* bfc = (const float*)d_in[12];
    float* out = (float*)d_out;

    const int E = in_sizes[1] / 2;
    const int* src = edge;
    const int* dst = edge + E;

    // workspace layout
    char* ws = (char*)d_ws;
    float* dsq    = (float*)ws;                   ws += sizeof(float) * N_NODES;
    int*   rowptr = (int*)ws;                     ws += sizeof(int) * (N_NODES + 1);
    int*   bcnt   = (int*)ws;                     ws += sizeof(int) * 256;
    int*   bstart = (int*)ws;                     ws += sizeof(int) * 256;
    int*   bcursor= (int*)ws;                     ws += sizeof(int) * 256;
    int*   gstart = (int*)ws;                     ws += sizeof(int) * (N_GRAPHS + 1);
    ws = (char*)(((size_t)ws + 15) & ~(size_t)15);
    uint*  xp3    = (uint*)ws;                    ws += sizeof(uint) * N_NODES * 4;
    int*   csr    = (int*)ws;                     ws += sizeof(int) * E;
    uint*  bufA   = (uint*)ws;                    ws += sizeof(uint) * N_NODES * 16;
    uint*  bufB   = (uint*)ws;                    ws += sizeof(uint) * N_NODES * 16;
    uint*  aggw   = (uint*)ws;                    ws += sizeof(uint) * N_NODES * 32;
    float* bufF   = (float*)ws;                   ws += sizeof(float) * N_NODES * EMB;
    uint*  sp     = (uint*)bufF;   // packed sorted pairs alias bufF (dead until layer 3)

    // ---- bucket sort + fused CSR build ----
    k_zero_i<<<1, 256, 0, stream>>>(bcnt, 256);
    k_bhist<<<512, 256, 0, stream>>>(dst, E, bcnt);
    k_bscan<<<1, 64, 0, stream>>>(bcnt, bstart, bcursor);
    k_bscatter<<<(E + CHUNK_E - 1) / CHUNK_E, 256, 0, stream>>>(src, dst, E, bcursor, sp);
    k_csr<<<NBKT, 512, 0, stream>>>(sp, bstart, rowptr, dsq, csr);
    k_gbound<<<(N_NODES + 255) / 256, 256, 0, stream>>>(batch, gstart);
    k_xprep3<<<512, 256, 0, stream>>>(x, dsq, xp3);

    // ---- 4 GCN layers (layer 0 fused; layers 1-3 split agg/mm) ----
    const int NBLK = N_NODES / 4;     // 25000 node-groups
    const int MGRID = 1024;           // few blocks: amortize W preload
    k_layer12<<<NBLK, 256, 0, stream>>>(rowptr, csr, dsq, xp3, W0, b0, bufA);

    k_agg<<<NBLK, 256, 0, stream>>>(rowptr, csr, dsq, (const uint2*)bufA, aggw);
    k_mmact<0, 0><<<MGRID, 256, 0, stream>>>(dsq, aggw, W1, b1, bufB, nullptr);

    k_agg<<<NBLK, 256, 0, stream>>>(rowptr, csr, dsq, (const uint2*)bufB, aggw);
    k_mmact<0, 0><<<MGRID, 256, 0, stream>>>(dsq, aggw, W2, b2, bufA, nullptr);

    k_agg<<<NBLK, 256, 0, stream>>>(rowptr, csr, dsq, (const uint2*)bufA, aggw);
    k_mmact<1, 1><<<MGRID, 256, 0, stream>>>(dsq, aggw, W3, b3, nullptr, bufF);

    // ---- fused mean pool + fc + sigmoid ----
    k_poolfc<<<N_GRAPHS, 256, 0, stream>>>(bufF, gstart, Wfc, bfc, out);
}